// Round 1
// baseline (679.598 us; speedup 1.0000x reference)
//
#include <hip/hip_runtime.h>
#include <hip/hip_bf16.h>

#define BB 32768
#define AA 64
#define HH 1024
#define DD 256
#define KK 4096

typedef __hip_bfloat16 bf16;
typedef __attribute__((ext_vector_type(8))) short bf16x8;
typedef __attribute__((ext_vector_type(4))) float f32x4;
typedef unsigned long long u64;

__device__ __forceinline__ float b2f(bf16 x) { return __bfloat162float(x); }
__device__ __forceinline__ bf16 f2b(float x) { return __float2bfloat16(x); }
__device__ __forceinline__ unsigned f2ord(float f) {
    unsigned u = __float_as_uint(f);
    return (u & 0x80000000u) ? ~u : (u | 0x80000000u);
}

// ---------------------------------------------------------------------------
// Prep: convert action to bf16; convert+transpose all weights to bf16 [N,K];
// convert codebook (already [N,K] for the VQ GEMM); codebook row norms.
// Block ranges (256 thr, 1024 elems/block unless noted):
//  [0,2048)    action f32->bf16              (2,097,152)
//  [ +64 )     enc_w1t  [1024x64]            (65,536)
//  [ +1024)    enc_w2t  [1024x1024]          (1,048,576)
//  [ +256 )    mu_wt    [256x1024]           (262,144)
//  [ +1024)    cb bf16  [4096x256]           (1,048,576)
//  [ +256 )    dec_w1t  [1024x256]           (262,144)
//  [ +1024)    dec_w2t  [1024x1024]          (1,048,576)
//  [ +128 )    dec_w3t  [128x1024] pad n>=64 (131,072)
//  [ +16  )    cnorm    4096 rows
// total blocks = 5840
// ---------------------------------------------------------------------------
__global__ void prep_kernel(const float* __restrict__ action,
                            const float* __restrict__ enc_w1,
                            const float* __restrict__ enc_w2,
                            const float* __restrict__ mu_w,
                            const float* __restrict__ codebook,
                            const float* __restrict__ dec_w1,
                            const float* __restrict__ dec_w2,
                            const float* __restrict__ dec_w3,
                            bf16* __restrict__ action_bf, bf16* __restrict__ ew1t,
                            bf16* __restrict__ ew2t, bf16* __restrict__ muwt,
                            bf16* __restrict__ cbb, bf16* __restrict__ dw1t,
                            bf16* __restrict__ dw2t, bf16* __restrict__ dw3t,
                            float* __restrict__ cnorm)
{
    int blk = blockIdx.x;
    const int t = threadIdx.x;
    if (blk < 2048) {
        int base = blk * 1024 + t;
#pragma unroll
        for (int i = 0; i < 4; i++) { int e = base + i * 256; action_bf[e] = f2b(action[e]); }
        return;
    }
    blk -= 2048;
    if (blk < 64) {  // enc_w1 (64,1024) -> [1024,64]
        int base = blk * 1024 + t;
#pragma unroll
        for (int i = 0; i < 4; i++) { int e = base + i * 256; int n = e >> 6, k = e & 63;
            ew1t[e] = f2b(enc_w1[k * HH + n]); }
        return;
    }
    blk -= 64;
    if (blk < 1024) {  // enc_w2 (1024,1024) -> T
        int base = blk * 1024 + t;
#pragma unroll
        for (int i = 0; i < 4; i++) { int e = base + i * 256; int n = e >> 10, k = e & 1023;
            ew2t[e] = f2b(enc_w2[k * HH + n]); }
        return;
    }
    blk -= 1024;
    if (blk < 256) {  // mu_w (1024,256) -> [256,1024]
        int base = blk * 1024 + t;
#pragma unroll
        for (int i = 0; i < 4; i++) { int e = base + i * 256; int n = e >> 10, k = e & 1023;
            muwt[e] = f2b(mu_w[k * DD + n]); }
        return;
    }
    blk -= 256;
    if (blk < 1024) {  // codebook convert (no transpose)
        int base = blk * 1024 + t;
#pragma unroll
        for (int i = 0; i < 4; i++) { int e = base + i * 256; cbb[e] = f2b(codebook[e]); }
        return;
    }
    blk -= 1024;
    if (blk < 256) {  // dec_w1 (256,1024) -> [1024,256]
        int base = blk * 1024 + t;
#pragma unroll
        for (int i = 0; i < 4; i++) { int e = base + i * 256; int n = e >> 8, k = e & 255;
            dw1t[e] = f2b(dec_w1[k * HH + n]); }
        return;
    }
    blk -= 256;
    if (blk < 1024) {  // dec_w2 (1024,1024) -> T
        int base = blk * 1024 + t;
#pragma unroll
        for (int i = 0; i < 4; i++) { int e = base + i * 256; int n = e >> 10, k = e & 1023;
            dw2t[e] = f2b(dec_w2[k * HH + n]); }
        return;
    }
    blk -= 1024;
    if (blk < 128) {  // dec_w3 (1024,64) -> [128,1024], pad rows n>=64 with 0
        int base = blk * 1024 + t;
#pragma unroll
        for (int i = 0; i < 4; i++) { int e = base + i * 256; int n = e >> 10, k = e & 1023;
            dw3t[e] = (n < AA) ? f2b(dec_w3[k * AA + n]) : f2b(0.0f); }
        return;
    }
    blk -= 128;
    {   // cnorm: one thread per codebook row
        int row = blk * 256 + t;
        float s = 0.f;
        for (int d = 0; d < DD; d++) { float v = codebook[row * DD + d]; s += v * v; }
        cnorm[row] = s;
    }
}

// ---------------------------------------------------------------------------
// GEMM: C[M,N] = A[M,K] * Bt[N,K]^T.  128x128 tile, 4 waves (2x2 of 64x64),
// 16x16x32 bf16 MFMA, BK=32, global_load_lds width-16 staging.
// EPI: 0 = bias+relu -> bf16 C     1 = bias -> bf16 C
//      2 = VQ argmin (cnorm - 2*dot -> u64 atomicMin keys)
//      3 = bias+tanh, SSE vs action -> partials[64+..] (no store)
// ---------------------------------------------------------------------------
template <int EPI>
__global__ __launch_bounds__(256) void gemm_bt(
    const bf16* __restrict__ A, const bf16* __restrict__ Bt,
    const float* __restrict__ bias, bf16* __restrict__ C,
    int N, int K,
    const float* __restrict__ cnorm, u64* __restrict__ keys,
    const float* __restrict__ actionf, float* __restrict__ partials)
{
    __shared__ __align__(16) bf16 sA[128 * 32];
    __shared__ __align__(16) bf16 sB[128 * 32];
    const int t = threadIdx.x;
    const int wave = t >> 6, lane = t & 63;
    const int quad = lane >> 4, l16 = lane & 15;
    const int wm = (wave >> 1) << 6, wn = (wave & 1) << 6;
    const int tile_m = blockIdx.y << 7;
    const int tile_n = blockIdx.x << 7;

    f32x4 acc[4][4];
#pragma unroll
    for (int i = 0; i < 4; i++)
#pragma unroll
        for (int j = 0; j < 4; j++) acc[i][j] = (f32x4){0.f, 0.f, 0.f, 0.f};

    for (int k0 = 0; k0 < K; k0 += 32) {
#pragma unroll
        for (int p = 0; p < 2; p++) {
            int c = p * 256 + t;             // chunk 0..511: row=c>>2, koff=(c&3)*8
            int row = c >> 2, ko = (c & 3) << 3;
            const bf16* ga = A + (long)(tile_m + row) * K + k0 + ko;
            const bf16* gb = Bt + (long)(tile_n + row) * K + k0 + ko;
            // LDS dest is wave-uniform base + lane*16
            char* la = (char*)sA + (p * 256 + wave * 64) * 16;
            char* lb = (char*)sB + (p * 256 + wave * 64) * 16;
            __builtin_amdgcn_global_load_lds((__attribute__((address_space(1))) unsigned int*)ga,
                                             (__attribute__((address_space(3))) unsigned int*)la, 16, 0, 0);
            __builtin_amdgcn_global_load_lds((__attribute__((address_space(1))) unsigned int*)gb,
                                             (__attribute__((address_space(3))) unsigned int*)lb, 16, 0, 0);
        }
        __syncthreads();
        bf16x8 af[4], bfr[4];
#pragma unroll
        for (int i = 0; i < 4; i++) {
            af[i]  = *(const bf16x8*)&sA[(wm + i * 16 + l16) * 32 + quad * 8];
            bfr[i] = *(const bf16x8*)&sB[(wn + i * 16 + l16) * 32 + quad * 8];
        }
#pragma unroll
        for (int i = 0; i < 4; i++)
#pragma unroll
            for (int j = 0; j < 4; j++)
                acc[i][j] = __builtin_amdgcn_mfma_f32_16x16x32_bf16(af[i], bfr[j], acc[i][j], 0, 0, 0);
        __syncthreads();
    }

    // C/D layout: col = lane&15, row = quad*4 + reg
    if (EPI == 0 || EPI == 1) {
#pragma unroll
        for (int i = 0; i < 4; i++) {
            int row = tile_m + wm + i * 16 + (quad << 2);
#pragma unroll
            for (int j = 0; j < 4; j++) {
                int col = tile_n + wn + j * 16 + l16;
                float bv = bias[col];
#pragma unroll
                for (int r = 0; r < 4; r++) {
                    float v = acc[i][j][r] + bv;
                    if (EPI == 0) v = fmaxf(v, 0.f);
                    C[(long)(row + r) * N + col] = f2b(v);
                }
            }
        }
    } else if (EPI == 2) {
#pragma unroll
        for (int i = 0; i < 4; i++) {
#pragma unroll
            for (int r = 0; r < 4; r++) {
                float best = 3.4e38f; int bi = 0;
#pragma unroll
                for (int j = 0; j < 4; j++) {
                    int col = tile_n + wn + j * 16 + l16;
                    float v = __builtin_fmaf(-2.f, acc[i][j][r], cnorm[col]);
                    if (v < best || (v == best && col < bi)) { best = v; bi = col; }
                }
#pragma unroll
                for (int off = 1; off < 16; off <<= 1) {
                    float ov = __shfl_xor(best, off);
                    int   oi = __shfl_xor(bi, off);
                    if (ov < best || (ov == best && oi < bi)) { best = ov; bi = oi; }
                }
                if (l16 == 0) {
                    int row = tile_m + wm + i * 16 + (quad << 2) + r;
                    u64 key = ((u64)f2ord(best) << 32) | (unsigned)bi;
                    atomicMin(&keys[row], key);
                }
            }
        }
    } else {  // EPI == 3
        float ls = 0.f;
#pragma unroll
        for (int i = 0; i < 4; i++) {
            int row = tile_m + wm + i * 16 + (quad << 2);
#pragma unroll
            for (int j = 0; j < 4; j++) {
                int col = tile_n + wn + j * 16 + l16;
                if (col < AA) {
                    float bv = bias[col];
#pragma unroll
                    for (int r = 0; r < 4; r++) {
                        float v = tanhf(acc[i][j][r] + bv);
                        float d = v - actionf[(long)(row + r) * AA + col];
                        ls += d * d;
                    }
                }
            }
        }
#pragma unroll
        for (int off = 32; off; off >>= 1) ls += __shfl_down(ls, off);
        __shared__ float wsum[4];
        if (lane == 0) wsum[wave] = ls;
        __syncthreads();
        if (t == 0) atomicAdd(&partials[64 + (blockIdx.y & 63)], wsum[0] + wsum[1] + wsum[2] + wsum[3]);
    }
}

// ---------------------------------------------------------------------------
// Gather q = codebook[idx] (bf16) and accumulate SSE(q - enc) -> partials[0..63]
// ---------------------------------------------------------------------------
__global__ void gather_vq(const u64* __restrict__ keys, const bf16* __restrict__ cb,
                          const bf16* __restrict__ enc, bf16* __restrict__ q,
                          float* __restrict__ partials)
{
    const int t = threadIdx.x;
    const int base = blockIdx.x * 4096;
    float s = 0.f;
#pragma unroll
    for (int e = 0; e < 16; e++) {
        int idx = base + e * 256 + t;
        int b = idx >> 8;
        int d = idx & 255;
        int code = (int)(keys[b] & 0xFFFFFFFFull);
        bf16 qv = cb[code * DD + d];
        q[idx] = qv;
        float df = b2f(qv) - b2f(enc[idx]);
        s += df * df;
    }
#pragma unroll
    for (int off = 32; off; off >>= 1) s += __shfl_down(s, off);
    __shared__ float wsum[4];
    int wave = t >> 6, lane = t & 63;
    if (lane == 0) wsum[wave] = s;
    __syncthreads();
    if (t == 0) atomicAdd(&partials[blockIdx.x & 63], wsum[0] + wsum[1] + wsum[2] + wsum[3]);
}

__global__ void finalize_kernel(const float* __restrict__ partials, float* __restrict__ out)
{
    int t = threadIdx.x;  // 64 threads
    float v = partials[t];
    float r = partials[64 + t];
#pragma unroll
    for (int off = 32; off; off >>= 1) { v += __shfl_down(v, off); r += __shfl_down(r, off); }
    if (t == 0) {
        float m = v * (1.f / ((float)BB * (float)DD));   // commitment == embedding (fwd)
        float vql = 1.25f * m;                           // 0.25*m + m
        float rl = r * (1.f / ((float)BB * (float)AA));
        out[0] = rl + vql;
        out[1] = rl;
        out[2] = vql;
        out[3] = m;
        out[4] = m;
    }
}

extern "C" void kernel_launch(void* const* d_in, const int* in_sizes, int n_in,
                              void* d_out, int out_size, void* d_ws, size_t ws_size,
                              hipStream_t stream)
{
    (void)in_sizes; (void)n_in; (void)out_size; (void)ws_size;
    const float* action   = (const float*)d_in[0];
    const float* enc_w1   = (const float*)d_in[1];
    const float* enc_b1   = (const float*)d_in[2];
    const float* enc_w2   = (const float*)d_in[3];
    const float* enc_b2   = (const float*)d_in[4];
    const float* mu_w     = (const float*)d_in[5];
    const float* mu_b     = (const float*)d_in[6];
    const float* codebook = (const float*)d_in[7];
    const float* dec_w1   = (const float*)d_in[8];
    const float* dec_b1   = (const float*)d_in[9];
    const float* dec_w2   = (const float*)d_in[10];
    const float* dec_b2   = (const float*)d_in[11];
    const float* dec_w3   = (const float*)d_in[12];
    const float* dec_b3   = (const float*)d_in[13];

    char* ws = (char*)d_ws;
    size_t off = 0;
    auto alloc = [&](size_t bytes) { char* p = ws + off; off += (bytes + 255) & ~(size_t)255; return p; };
    bf16* action_bf = (bf16*)alloc((size_t)BB * AA * 2);   // 4 MB
    bf16* ew1t      = (bf16*)alloc((size_t)HH * AA * 2);   // 128 KB
    bf16* ew2t      = (bf16*)alloc((size_t)HH * HH * 2);   // 2 MB
    bf16* muwt      = (bf16*)alloc((size_t)DD * HH * 2);   // 512 KB
    bf16* cbb       = (bf16*)alloc((size_t)KK * DD * 2);   // 2 MB
    bf16* dw1t      = (bf16*)alloc((size_t)HH * DD * 2);   // 512 KB
    bf16* dw2t      = (bf16*)alloc((size_t)HH * HH * 2);   // 2 MB
    bf16* dw3t      = (bf16*)alloc((size_t)128 * HH * 2);  // 256 KB
    float* cnorm    = (float*)alloc((size_t)KK * 4);
    u64* keys       = (u64*)alloc((size_t)BB * 8);         // 256 KB
    float* partials = (float*)alloc(128 * 4);
    bf16* h1        = (bf16*)alloc((size_t)BB * HH * 2);   // 64 MB
    bf16* h2        = (bf16*)alloc((size_t)BB * HH * 2);   // 64 MB
    bf16* encb      = (bf16*)alloc((size_t)BB * DD * 2);   // 16 MB
    bf16* qb        = (bf16*)alloc((size_t)BB * DD * 2);   // 16 MB

    hipMemsetAsync(keys, 0xFF, (size_t)BB * 8, stream);
    hipMemsetAsync(partials, 0, 128 * 4, stream);

    prep_kernel<<<5840, 256, 0, stream>>>(action, enc_w1, enc_w2, mu_w, codebook,
                                          dec_w1, dec_w2, dec_w3,
                                          action_bf, ew1t, ew2t, muwt, cbb, dw1t, dw2t, dw3t, cnorm);

    // encoder
    gemm_bt<0><<<dim3(HH / 128, BB / 128), 256, 0, stream>>>(action_bf, ew1t, enc_b1, h1, HH, AA,
                                                             nullptr, nullptr, nullptr, nullptr);
    gemm_bt<0><<<dim3(HH / 128, BB / 128), 256, 0, stream>>>(h1, ew2t, enc_b2, h2, HH, HH,
                                                             nullptr, nullptr, nullptr, nullptr);
    gemm_bt<1><<<dim3(DD / 128, BB / 128), 256, 0, stream>>>(h2, muwt, mu_b, encb, DD, HH,
                                                             nullptr, nullptr, nullptr, nullptr);
    // VQ: argmin over codebook of cnorm[k] - 2*enc.c_k
    gemm_bt<2><<<dim3(KK / 128, BB / 128), 256, 0, stream>>>(encb, cbb, nullptr, nullptr, KK, DD,
                                                             cnorm, keys, nullptr, nullptr);
    gather_vq<<<(BB * DD) / 4096, 256, 0, stream>>>(keys, cbb, encb, qb, partials);
    // decoder
    gemm_bt<0><<<dim3(HH / 128, BB / 128), 256, 0, stream>>>(qb, dw1t, dec_b1, h1, HH, DD,
                                                             nullptr, nullptr, nullptr, nullptr);
    gemm_bt<0><<<dim3(HH / 128, BB / 128), 256, 0, stream>>>(h1, dw2t, dec_b2, h2, HH, HH,
                                                             nullptr, nullptr, nullptr, nullptr);
    gemm_bt<3><<<dim3(1, BB / 128), 256, 0, stream>>>(h2, dw3t, dec_b3, nullptr, 128, HH,
                                                      nullptr, nullptr, action, partials);

    finalize_kernel<<<1, 64, 0, stream>>>(partials, (float*)d_out);
}

// Round 2
// 640.449 us; speedup vs baseline: 1.0611x; 1.0611x over previous
//
#include <hip/hip_runtime.h>
#include <hip/hip_bf16.h>

#define BB 32768
#define AA 64
#define HH 1024
#define DD 256
#define KK 4096

typedef __hip_bfloat16 bf16;
typedef __attribute__((ext_vector_type(8))) short bf16x8;
typedef __attribute__((ext_vector_type(4))) float f32x4;
typedef unsigned long long u64;

__device__ __forceinline__ float b2f(bf16 x) { return __bfloat162float(x); }
__device__ __forceinline__ bf16 f2b(float x) { return __float2bfloat16(x); }
__device__ __forceinline__ unsigned f2ord(float f) {
    unsigned u = __float_as_uint(f);
    return (u & 0x80000000u) ? ~u : (u | 0x80000000u);
}

// ---------------------------------------------------------------------------
// Prep: convert action to bf16; convert+transpose all weights to bf16 [N,K];
// codebook bf16 (already [N,K]); codebook row norms.
// ---------------------------------------------------------------------------
__global__ void prep_kernel(const float* __restrict__ action,
                            const float* __restrict__ enc_w1,
                            const float* __restrict__ enc_w2,
                            const float* __restrict__ mu_w,
                            const float* __restrict__ codebook,
                            const float* __restrict__ dec_w1,
                            const float* __restrict__ dec_w2,
                            const float* __restrict__ dec_w3,
                            bf16* __restrict__ action_bf, bf16* __restrict__ ew1t,
                            bf16* __restrict__ ew2t, bf16* __restrict__ muwt,
                            bf16* __restrict__ cbb, bf16* __restrict__ dw1t,
                            bf16* __restrict__ dw2t, bf16* __restrict__ dw3t,
                            float* __restrict__ cnorm)
{
    int blk = blockIdx.x;
    const int t = threadIdx.x;
    if (blk < 2048) {
        int base = blk * 1024 + t;
#pragma unroll
        for (int i = 0; i < 4; i++) { int e = base + i * 256; action_bf[e] = f2b(action[e]); }
        return;
    }
    blk -= 2048;
    if (blk < 64) {  // enc_w1 (64,1024) -> [1024,64]
        int base = blk * 1024 + t;
#pragma unroll
        for (int i = 0; i < 4; i++) { int e = base + i * 256; int n = e >> 6, k = e & 63;
            ew1t[e] = f2b(enc_w1[k * HH + n]); }
        return;
    }
    blk -= 64;
    if (blk < 1024) {  // enc_w2 (1024,1024) -> T
        int base = blk * 1024 + t;
#pragma unroll
        for (int i = 0; i < 4; i++) { int e = base + i * 256; int n = e >> 10, k = e & 1023;
            ew2t[e] = f2b(enc_w2[k * HH + n]); }
        return;
    }
    blk -= 1024;
    if (blk < 256) {  // mu_w (1024,256) -> [256,1024]
        int base = blk * 1024 + t;
#pragma unroll
        for (int i = 0; i < 4; i++) { int e = base + i * 256; int n = e >> 10, k = e & 1023;
            muwt[e] = f2b(mu_w[k * DD + n]); }
        return;
    }
    blk -= 256;
    if (blk < 1024) {  // codebook convert (no transpose)
        int base = blk * 1024 + t;
#pragma unroll
        for (int i = 0; i < 4; i++) { int e = base + i * 256; cbb[e] = f2b(codebook[e]); }
        return;
    }
    blk -= 1024;
    if (blk < 256) {  // dec_w1 (256,1024) -> [1024,256]
        int base = blk * 1024 + t;
#pragma unroll
        for (int i = 0; i < 4; i++) { int e = base + i * 256; int n = e >> 8, k = e & 255;
            dw1t[e] = f2b(dec_w1[k * HH + n]); }
        return;
    }
    blk -= 256;
    if (blk < 1024) {  // dec_w2 (1024,1024) -> T
        int base = blk * 1024 + t;
#pragma unroll
        for (int i = 0; i < 4; i++) { int e = base + i * 256; int n = e >> 10, k = e & 1023;
            dw2t[e] = f2b(dec_w2[k * HH + n]); }
        return;
    }
    blk -= 1024;
    if (blk < 128) {  // dec_w3 (1024,64) -> [128,1024], pad rows n>=64 with 0
        int base = blk * 1024 + t;
#pragma unroll
        for (int i = 0; i < 4; i++) { int e = base + i * 256; int n = e >> 10, k = e & 1023;
            dw3t[e] = (n < AA) ? f2b(dec_w3[k * AA + n]) : f2b(0.0f); }
        return;
    }
    blk -= 128;
    {   // cnorm: one thread per codebook row
        int row = blk * 256 + t;
        float s = 0.f;
        for (int d = 0; d < DD; d++) { float v = codebook[row * DD + d]; s += v * v; }
        cnorm[row] = s;
    }
}

// ---------------------------------------------------------------------------
// GEMM: C[M,N] = A[M,K] * Bt[N,K]^T.  128x128 tile, 4 waves (2x2 of 64x64),
// 16x16x32 bf16 MFMA, BK=64, XOR-swizzled LDS (conflict-free ds_read_b128),
// global_load_lds width-16 staging, compile-time N/K.
// EPI: 0 = bias+relu -> bf16 C     1 = bias -> bf16 C
//      2 = VQ argmin (cnorm - 2*dot -> u64 atomicMin keys)
//      3 = bias+tanh, SSE vs action -> partials[64+..] (no store)
// ---------------------------------------------------------------------------
template <int N, int K, int EPI>
__global__ __launch_bounds__(256) void gemm_bt(
    const bf16* __restrict__ A, const bf16* __restrict__ Bt,
    const float* __restrict__ bias, bf16* __restrict__ C,
    const float* __restrict__ cnorm, u64* __restrict__ keys,
    const float* __restrict__ actionf, float* __restrict__ partials)
{
    __shared__ __align__(16) bf16 sA[128 * 64];   // 16 KB, rows of 128 B, swizzled
    __shared__ __align__(16) bf16 sB[128 * 64];   // 16 KB
    const int t = threadIdx.x;
    const int wave = t >> 6, lane = t & 63;
    const int quad = lane >> 4, l16 = lane & 15;
    const int wm = (wave >> 1) << 6, wn = (wave & 1) << 6;
    const long tile_m = (long)blockIdx.y << 7;
    const int tile_n = blockIdx.x << 7;

    // Staging: chunk c = q*256 + t  (q=0..3 per tile).  LDS position = c*16 bytes.
    // Position (row, q') holds global 16B-chunk q = q' ^ (row & 7)  [XOR swizzle].
    // row = c>>3 = q*32 + (t>>3);  q' = c&7 = t&7  -> ko same for all q.
    const int arow = t >> 3;                              // 0..31
    const int ko = (((t & 7) ^ (arow & 7)) << 3);         // element offset in row
    const bf16* ga[4];
    const bf16* gb[4];
#pragma unroll
    for (int q = 0; q < 4; q++) {
        ga[q] = A + (tile_m + q * 32 + arow) * K + ko;
        gb[q] = Bt + (long)(tile_n + q * 32 + arow) * K + ko;
    }

    f32x4 acc[4][4];
#pragma unroll
    for (int i = 0; i < 4; i++)
#pragma unroll
        for (int j = 0; j < 4; j++) acc[i][j] = (f32x4){0.f, 0.f, 0.f, 0.f};

    for (int k0 = 0; k0 < K; k0 += 64) {
#pragma unroll
        for (int q = 0; q < 4; q++) {
            char* la = (char*)sA + (q * 256 + wave * 64) * 16;
            char* lb = (char*)sB + (q * 256 + wave * 64) * 16;
            __builtin_amdgcn_global_load_lds((const __attribute__((address_space(1))) unsigned int*)ga[q],
                                             (__attribute__((address_space(3))) unsigned int*)la, 16, 0, 0);
            __builtin_amdgcn_global_load_lds((const __attribute__((address_space(1))) unsigned int*)gb[q],
                                             (__attribute__((address_space(3))) unsigned int*)lb, 16, 0, 0);
            ga[q] += 64; gb[q] += 64;
        }
        __syncthreads();
#pragma unroll
        for (int ks = 0; ks < 2; ks++) {
            bf16x8 af[4], bfr[4];
#pragma unroll
            for (int i = 0; i < 4; i++) {
                int ra = wm + i * 16 + l16;
                int qa = ((ks << 2) | quad) ^ (l16 & 7);
                af[i] = *(const bf16x8*)&sA[ra * 64 + qa * 8];
                int rb = wn + i * 16 + l16;
                bfr[i] = *(const bf16x8*)&sB[rb * 64 + qa * 8];
            }
#pragma unroll
            for (int i = 0; i < 4; i++)
#pragma unroll
                for (int j = 0; j < 4; j++)
                    acc[i][j] = __builtin_amdgcn_mfma_f32_16x16x32_bf16(af[i], bfr[j], acc[i][j], 0, 0, 0);
        }
        __syncthreads();
    }

    // C/D layout: col = lane&15, row = quad*4 + reg
    if (EPI == 0 || EPI == 1) {
#pragma unroll
        for (int i = 0; i < 4; i++) {
            int row = (int)tile_m + wm + i * 16 + (quad << 2);
#pragma unroll
            for (int j = 0; j < 4; j++) {
                int col = tile_n + wn + j * 16 + l16;
                float bv = bias[col];
#pragma unroll
                for (int r = 0; r < 4; r++) {
                    float v = acc[i][j][r] + bv;
                    if (EPI == 0) v = fmaxf(v, 0.f);
                    bf16 b = f2b(v);
                    int mine = (int)*(unsigned short*)&b;
                    int oth = __shfl_xor(mine, 1);
                    if (!(l16 & 1)) {
                        unsigned packed = (unsigned)mine | ((unsigned)oth << 16);
                        *(unsigned*)((char*)C + ((long)(row + r) * N + col) * 2) = packed;
                    }
                }
            }
        }
    } else if (EPI == 2) {
#pragma unroll
        for (int i = 0; i < 4; i++) {
#pragma unroll
            for (int r = 0; r < 4; r++) {
                float best = 3.4e38f; int bi = 0;
#pragma unroll
                for (int j = 0; j < 4; j++) {
                    int col = tile_n + wn + j * 16 + l16;
                    float v = __builtin_fmaf(-2.f, acc[i][j][r], cnorm[col]);
                    if (v < best || (v == best && col < bi)) { best = v; bi = col; }
                }
#pragma unroll
                for (int off = 1; off < 16; off <<= 1) {
                    float ov = __shfl_xor(best, off);
                    int   oi = __shfl_xor(bi, off);
                    if (ov < best || (ov == best && oi < bi)) { best = ov; bi = oi; }
                }
                if (l16 == 0) {
                    int row = (int)tile_m + wm + i * 16 + (quad << 2) + r;
                    u64 key = ((u64)f2ord(best) << 32) | (unsigned)bi;
                    atomicMin(&keys[row], key);
                }
            }
        }
    } else {  // EPI == 3: tanh + SSE vs action (cols >= AA are zero-padded)
        float ls = 0.f;
#pragma unroll
        for (int i = 0; i < 4; i++) {
            int row = (int)tile_m + wm + i * 16 + (quad << 2);
#pragma unroll
            for (int j = 0; j < 4; j++) {
                int col = tile_n + wn + j * 16 + l16;
                if (col < AA) {
                    float bv = bias[col];
#pragma unroll
                    for (int r = 0; r < 4; r++) {
                        float v = tanhf(acc[i][j][r] + bv);
                        float d = v - actionf[(long)(row + r) * AA + col];
                        ls += d * d;
                    }
                }
            }
        }
#pragma unroll
        for (int off = 32; off; off >>= 1) ls += __shfl_down(ls, off);
        __shared__ float wsum[4];
        if (lane == 0) wsum[wave] = ls;
        __syncthreads();
        if (t == 0) atomicAdd(&partials[64 + (blockIdx.y & 63)], wsum[0] + wsum[1] + wsum[2] + wsum[3]);
    }
}

// ---------------------------------------------------------------------------
// Gather q = codebook[idx] (bf16) and accumulate SSE(q - enc) -> partials[0..63]
// ---------------------------------------------------------------------------
__global__ void gather_vq(const u64* __restrict__ keys, const bf16* __restrict__ cb,
                          const bf16* __restrict__ enc, bf16* __restrict__ q,
                          float* __restrict__ partials)
{
    const int t = threadIdx.x;
    const int base = blockIdx.x * 4096;
    float s = 0.f;
#pragma unroll
    for (int e = 0; e < 16; e++) {
        int idx = base + e * 256 + t;
        int b = idx >> 8;
        int d = idx & 255;
        int code = (int)(keys[b] & 0xFFFFFFFFull);
        bf16 qv = cb[code * DD + d];
        q[idx] = qv;
        float df = b2f(qv) - b2f(enc[idx]);
        s += df * df;
    }
#pragma unroll
    for (int off = 32; off; off >>= 1) s += __shfl_down(s, off);
    __shared__ float wsum[4];
    int wave = t >> 6, lane = t & 63;
    if (lane == 0) wsum[wave] = s;
    __syncthreads();
    if (t == 0) atomicAdd(&partials[blockIdx.x & 63], wsum[0] + wsum[1] + wsum[2] + wsum[3]);
}

__global__ void finalize_kernel(const float* __restrict__ partials, float* __restrict__ out)
{
    int t = threadIdx.x;  // 64 threads
    float v = partials[t];
    float r = partials[64 + t];
#pragma unroll
    for (int off = 32; off; off >>= 1) { v += __shfl_down(v, off); r += __shfl_down(r, off); }
    if (t == 0) {
        float m = v * (1.f / ((float)BB * (float)DD));   // commitment == embedding (fwd)
        float vql = 1.25f * m;                           // 0.25*m + m
        float rl = r * (1.f / ((float)BB * (float)AA));
        out[0] = rl + vql;
        out[1] = rl;
        out[2] = vql;
        out[3] = m;
        out[4] = m;
    }
}

extern "C" void kernel_launch(void* const* d_in, const int* in_sizes, int n_in,
                              void* d_out, int out_size, void* d_ws, size_t ws_size,
                              hipStream_t stream)
{
    (void)in_sizes; (void)n_in; (void)out_size; (void)ws_size;
    const float* action   = (const float*)d_in[0];
    const float* enc_w1   = (const float*)d_in[1];
    const float* enc_b1   = (const float*)d_in[2];
    const float* enc_w2   = (const float*)d_in[3];
    const float* enc_b2   = (const float*)d_in[4];
    const float* mu_w     = (const float*)d_in[5];
    const float* mu_b     = (const float*)d_in[6];
    const float* codebook = (const float*)d_in[7];
    const float* dec_w1   = (const float*)d_in[8];
    const float* dec_b1   = (const float*)d_in[9];
    const float* dec_w2   = (const float*)d_in[10];
    const float* dec_b2   = (const float*)d_in[11];
    const float* dec_w3   = (const float*)d_in[12];
    const float* dec_b3   = (const float*)d_in[13];

    char* ws = (char*)d_ws;
    size_t off = 0;
    auto alloc = [&](size_t bytes) { char* p = ws + off; off += (bytes + 255) & ~(size_t)255; return p; };
    bf16* action_bf = (bf16*)alloc((size_t)BB * AA * 2);   // 4 MB
    bf16* ew1t      = (bf16*)alloc((size_t)HH * AA * 2);   // 128 KB
    bf16* ew2t      = (bf16*)alloc((size_t)HH * HH * 2);   // 2 MB
    bf16* muwt      = (bf16*)alloc((size_t)DD * HH * 2);   // 512 KB
    bf16* cbb       = (bf16*)alloc((size_t)KK * DD * 2);   // 2 MB
    bf16* dw1t      = (bf16*)alloc((size_t)HH * DD * 2);   // 512 KB
    bf16* dw2t      = (bf16*)alloc((size_t)HH * HH * 2);   // 2 MB
    bf16* dw3t      = (bf16*)alloc((size_t)128 * HH * 2);  // 256 KB
    float* cnorm    = (float*)alloc((size_t)KK * 4);
    u64* keys       = (u64*)alloc((size_t)BB * 8);         // 256 KB
    float* partials = (float*)alloc(128 * 4);
    bf16* h1        = (bf16*)alloc((size_t)BB * HH * 2);   // 64 MB
    bf16* h2        = (bf16*)alloc((size_t)BB * HH * 2);   // 64 MB
    bf16* encb      = (bf16*)alloc((size_t)BB * DD * 2);   // 16 MB
    bf16* qb        = (bf16*)alloc((size_t)BB * DD * 2);   // 16 MB

    hipMemsetAsync(keys, 0xFF, (size_t)BB * 8, stream);
    hipMemsetAsync(partials, 0, 128 * 4, stream);

    prep_kernel<<<5840, 256, 0, stream>>>(action, enc_w1, enc_w2, mu_w, codebook,
                                          dec_w1, dec_w2, dec_w3,
                                          action_bf, ew1t, ew2t, muwt, cbb, dw1t, dw2t, dw3t, cnorm);

    // encoder
    gemm_bt<HH, AA, 0><<<dim3(HH / 128, BB / 128), 256, 0, stream>>>(action_bf, ew1t, enc_b1, h1,
                                                                     nullptr, nullptr, nullptr, nullptr);
    gemm_bt<HH, HH, 0><<<dim3(HH / 128, BB / 128), 256, 0, stream>>>(h1, ew2t, enc_b2, h2,
                                                                     nullptr, nullptr, nullptr, nullptr);
    gemm_bt<DD, HH, 1><<<dim3(DD / 128, BB / 128), 256, 0, stream>>>(h2, muwt, mu_b, encb,
                                                                     nullptr, nullptr, nullptr, nullptr);
    // VQ: argmin over codebook of cnorm[k] - 2*enc.c_k
    gemm_bt<KK, DD, 2><<<dim3(KK / 128, BB / 128), 256, 0, stream>>>(encb, cbb, nullptr, nullptr,
                                                                     cnorm, keys, nullptr, nullptr);
    gather_vq<<<(BB * DD) / 4096, 256, 0, stream>>>(keys, cbb, encb, qb, partials);
    // decoder
    gemm_bt<HH, DD, 0><<<dim3(HH / 128, BB / 128), 256, 0, stream>>>(qb, dw1t, dec_b1, h1,
                                                                     nullptr, nullptr, nullptr, nullptr);
    gemm_bt<HH, HH, 0><<<dim3(HH / 128, BB / 128), 256, 0, stream>>>(h1, dw2t, dec_b2, h2,
                                                                     nullptr, nullptr, nullptr, nullptr);
    gemm_bt<128, HH, 3><<<dim3(1, BB / 128), 256, 0, stream>>>(h2, dw3t, dec_b3, nullptr,
                                                               nullptr, nullptr, action, partials);

    finalize_kernel<<<1, 64, 0, stream>>>(partials, (float*)d_out);
}